// Round 12
// baseline (4097.530 us; speedup 1.0000x reference)
//
#include <hip/hip_runtime.h>
#include <math.h>

#define N 64
#define VP 65            // odd pitch: all row/col/diag accesses spread banks (2-way max)
#define SWEEPS 6         // 5 sweeps FAILED (r8, absmax 0.30); adaptive check cost > savings (r10)
#define EPSV 1e-3
#define MAXEIG 1000.0

// EIGHT 64-lane waves per 64x64 symmetric matrix (512 threads/block).
// FUSED parallel Jacobi round: the 32 disjoint rotations of a tournament
// round make A <- J^T A J decompose into 1024 independent 2x2 blocks
// A[{p1,q1},{p2,q2}] <- L(i1)^T blk R(i2). Each lane handles 2 blocks
// (i1 = 4*wid + 2*half + b, i2 = lane&31) -> A read ONCE + written ONCE per
// round (was twice in the row/col two-phase scheme), and A is DOUBLE-BUFFERED
// (read old, write new) so each round needs exactly ONE barrier (378 total,
// was 756): round r's reads of buf[r&1] all precede the round barrier; the
// next write to buf[r&1] is in round r+1, after it.
// Every lane computes its own pair's (c,s) (i2 = lane&31) -> R-coefficients
// are lane-local (no shuffle); L-coefficients via 4 ds_bpermute; Vt
// coefficients via readlane -> SGPRs. Odd pitch 65 everywhere (round 11
// lesson: even pitch made column access a real 4-way conflict, 4e8 cycles).
__global__ __launch_bounds__(512, 6)
void spd_log_kernel(const float* __restrict__ x, float* __restrict__ out) {
    __shared__ __align__(16) float Abuf[2][N * VP];  // double-buffered A
    __shared__ float Vt_[N * VP];                    // V^T; row k = eigenvector k
    __shared__ float farr[N];

    const int tid  = (int)threadIdx.x;
    const int lane = tid & 63;
    const int wid  = __builtin_amdgcn_readfirstlane(tid >> 6);  // 0..7
    const int hb   = lane >> 5;
    const size_t mat = blockIdx.x;
    const float* __restrict__ xm = x + mat * (size_t)(N * N);
    float* __restrict__ om = out + mat * (size_t)(N * N);

#pragma unroll
    for (int t = 0; t < 8; ++t) {
        const int r2 = wid * 8 + t;
        Abuf[0][r2 * VP + lane] = xm[r2 * N + lane];
        Vt_[r2 * VP + lane] = (r2 == lane) ? 1.0f : 0.0f;
    }
    __syncthreads();

    int par = 0;
    for (int sweep = 0; sweep < SWEEPS; ++sweep) {
        for (int r = 0; r < N - 1; ++r) {
            float* __restrict__ Ao = Abuf[par];
            float* __restrict__ An = Abuf[par ^ 1];
            par ^= 1;

            // ---- own pair i2 = lane&31: indices + rotation coeffs (all lanes,
            //      duplicated across halves so R-coeffs are lane-local) ----
            const int i2 = lane & 31;
            int a2 = i2 - 1 + r; if (a2 >= 63) a2 -= 63;
            const int p2 = (i2 == 0) ? 0 : 1 + a2;
            int b2 = 62 - i2 + r; if (b2 >= 63) b2 -= 63;
            const int q2 = 1 + b2;

            const float app = Ao[p2 * VP + p2];
            const float aqq = Ao[q2 * VP + q2];
            const float apq = Ao[p2 * VP + q2];
            const float tau = (aqq - app) * (0.5f * __builtin_amdgcn_rcpf(apq));
            const float at  = fabsf(tau);
            float tt = __builtin_amdgcn_rcpf(at + __builtin_amdgcn_sqrtf(fmaf(at, at, 1.0f)));
            tt = copysignf(tt, tau);
            const float ccf = __builtin_amdgcn_rsqf(fmaf(tt, tt, 1.0f));
            const bool tiny = !(fabsf(apq) > 1e-30f);   // also guards NaN path
            const float cv = tiny ? 1.0f : ccf;
            const float sv = tiny ? 0.0f : tt * ccf;

            // ---- L coeffs for this lane's two row-pairs (i1 = ibase, ibase+1) ----
            const int ibase = 4 * wid + 2 * hb;
            const float c1a = __shfl(cv, ibase),     s1a = __shfl(sv, ibase);
            const float c1b = __shfl(cv, ibase + 1), s1b = __shfl(sv, ibase + 1);
            int a1 = ibase - 1 + r; if (a1 >= 63) a1 -= 63;
            const int p1a = (ibase == 0) ? 0 : 1 + a1;
            int b1 = 62 - ibase + r; if (b1 >= 63) b1 -= 63;
            const int q1a = 1 + b1;
            int a1b = ibase + r; if (a1b >= 63) a1b -= 63;     // i1 = ibase+1 >= 1
            const int p1b = 1 + a1b;
            int b1b = 61 - ibase + r; if (b1b >= 63) b1b -= 63;
            const int q1b = 1 + b1b;

            // ---- Vt coeffs/indices for this wave's 4 pairs (SGPR) ----
            float cs4[4], ss4[4];
            int pa[4], qa[4];
#pragma unroll
            for (int ii = 0; ii < 4; ++ii) {
                const int i = 4 * wid + ii;
                cs4[ii] = __uint_as_float(__builtin_amdgcn_readlane(__float_as_uint(cv), i));
                ss4[ii] = __uint_as_float(__builtin_amdgcn_readlane(__float_as_uint(sv), i));
                int a = i - 1 + r; if (a >= 63) a -= 63;
                pa[ii] = (i == 0) ? 0 : 1 + a;
                int b = 62 - i + r; if (b >= 63) b -= 63;
                qa[ii] = 1 + b;
            }

            // ---- gather both 2x2 blocks + Vt pairs (all reads first) ----
            const float m00a = Ao[p1a * VP + p2], m01a = Ao[p1a * VP + q2];
            const float m10a = Ao[q1a * VP + p2], m11a = Ao[q1a * VP + q2];
            const float m00b = Ao[p1b * VP + p2], m01b = Ao[p1b * VP + q2];
            const float m10b = Ao[q1b * VP + p2], m11b = Ao[q1b * VP + q2];
            float vp[4], vq[4];
#pragma unroll
            for (int ii = 0; ii < 4; ++ii) {
                vp[ii] = Vt_[pa[ii] * VP + lane];
                vq[ii] = Vt_[qa[ii] * VP + lane];
            }

            // ---- block a: right rot (cv,sv) then left rot (c1a,s1a) ----
            {
                const float t0 = cv * m00a - sv * m01a;
                const float t1 = sv * m00a + cv * m01a;
                const float t2 = cv * m10a - sv * m11a;
                const float t3 = sv * m10a + cv * m11a;
                An[p1a * VP + p2] = c1a * t0 - s1a * t2;
                An[p1a * VP + q2] = c1a * t1 - s1a * t3;
                An[q1a * VP + p2] = s1a * t0 + c1a * t2;
                An[q1a * VP + q2] = s1a * t1 + c1a * t3;
            }
            // ---- block b ----
            {
                const float t0 = cv * m00b - sv * m01b;
                const float t1 = sv * m00b + cv * m01b;
                const float t2 = cv * m10b - sv * m11b;
                const float t3 = sv * m10b + cv * m11b;
                An[p1b * VP + p2] = c1b * t0 - s1b * t2;
                An[p1b * VP + q2] = c1b * t1 - s1b * t3;
                An[q1b * VP + p2] = s1b * t0 + c1b * t2;
                An[q1b * VP + q2] = s1b * t1 + c1b * t3;
            }
            // ---- Vt row rotations (wave-own rows, in place) ----
#pragma unroll
            for (int ii = 0; ii < 4; ++ii) {
                Vt_[pa[ii] * VP + lane] = cs4[ii] * vp[ii] - ss4[ii] * vq[ii];
                Vt_[qa[ii] * VP + lane] = ss4[ii] * vp[ii] + cs4[ii] * vq[ii];
            }
            __syncthreads();   // the ONLY barrier per round
        }
    }

    // A is dead from here -> overlay Rayleigh partials on its storage.
    double2* part = reinterpret_cast<double2*>(&Abuf[0][0]);

    // ---- fp64 Rayleigh vs ORIGINAL input; eigvec `lane` = Vt row `lane`;
    //      each wave covers 8 rows of the quadratic form ----
    const int r0 = wid * 8;
    {
        float vr[8];
#pragma unroll
        for (int t = 0; t < 8; ++t) vr[t] = Vt_[lane * VP + r0 + t];
        double nrm = 0.0, acc = 0.0;
#pragma unroll
        for (int t = 0; t < 8; ++t) nrm += (double)vr[t] * (double)vr[t];
        for (int c = 0; c < N; ++c) {
            const double vc = (double)Vt_[lane * VP + c];
            double inner = 0.0;
#pragma unroll
            for (int t = 0; t < 8; ++t)
                inner += (double)xm[(r0 + t) * N + c] * (double)vr[t];
            acc += vc * inner;
        }
        if (wid > 0) part[(wid - 1) * N + lane] = make_double2(acc, nrm);
        __syncthreads();
        if (wid == 0) {
#pragma unroll
            for (int k = 0; k < 7; ++k) {
                acc += part[k * N + lane].x;
                nrm += part[k * N + lane].y;
            }
            double wv = acc / nrm;
            wv = fmin(fmax(wv, (double)EPSV), (double)MAXEIG);
            farr[lane] = (float)log(wv);
        }
    }
    __syncthreads();

    // ---- reconstruct Out[r][lane] = sum_j Vt[j][r] * f_j * Vt[j][lane];
    //      8 rows per wave; Vt[j][r0+t] is a uniform broadcast read ----
    {
        float acc8[8];
#pragma unroll
        for (int t = 0; t < 8; ++t) acc8[t] = 0.0f;
        for (int j = 0; j < N; ++j) {
            const float gj = Vt_[j * VP + lane] * farr[j];
#pragma unroll
            for (int t = 0; t < 8; ++t)
                acc8[t] += Vt_[j * VP + r0 + t] * gj;
        }
#pragma unroll
        for (int t = 0; t < 8; ++t)
            om[(r0 + t) * N + lane] = acc8[t];
    }
}

extern "C" void kernel_launch(void* const* d_in, const int* in_sizes, int n_in,
                              void* d_out, int out_size, void* d_ws, size_t ws_size,
                              hipStream_t stream) {
    const float* x = (const float*)d_in[0];
    float* out = (float*)d_out;
    const int nmat = in_sizes[0] / (N * N);
    spd_log_kernel<<<dim3(nmat), dim3(512), 0, stream>>>(x, out);
}

// Round 13
// 4021.400 us; speedup vs baseline: 1.0189x; 1.0189x over previous
//
#include <hip/hip_runtime.h>
#include <math.h>

#define N 64
#define NP 65            // ODD pitch: col phase banks (lane+p)%32 conflict-free (r11 lesson:
                         // even pitch made col phase 4-way, 4e8 conflict cycles)
#define SWEEPS 6         // 5 sweeps FAILED (r8, absmax 0.30); adaptive check cost > savings (r10)
#define EPSV 1e-3
#define MAXEIG 1000.0

// EIGHT 64-lane waves per 64x64 symmetric matrix (512 threads/block).
// Two-sided cyclic Jacobi, tournament ordering; 32 pairs/round, 4 per wave.
// Structure = round 9 (two phases, odd pitch, conflict-free banking) +
// round 11's instruction cut: row & Vt rotations process TWO ADJACENT dword
// columns per lane (half-wave per pair). At odd pitch the two adjacent
// accesses can't be a b64, but ds_read2_b32/ds_write2_b32 take two dword
// offsets with 4B alignment -> still ONE LDS instruction for 2 values.
// Row-phase banks: (pg + 2*cl)%32 = 16 banks x 2-way per half, halves offset
// by 1 -> 32 banks 2-way total = free (m136). Coefficients computed on 4
// lanes only (all-lane redundant coeff reads were round 12's 32-way storm:
// bank (p2+q2)%32 is ~constant across the tournament's pairs).
// NO fused one-barrier scheme (round 12: scattered 2x2 blocks cost more in
// conflicts + VALU than the saved barrier).
__global__ __launch_bounds__(512, 8)
void spd_log_kernel(const float* __restrict__ x, float* __restrict__ out) {
    __shared__ __align__(16) float buf[2 * N * NP];  // [0,64): A ; [64,128): Vt
    __shared__ float farr[N];

    float* const As_ = buf;
    float* const Vt_ = buf + N * NP;   // Vt row k = eigenvector k

    const int tid  = (int)threadIdx.x;
    const int lane = tid & 63;
    const int wid  = __builtin_amdgcn_readfirstlane(tid >> 6);  // 0..7
    const int half = lane >> 5;        // which pair of each group this lane serves
    const int c2   = (lane & 31) * 2;  // two adjacent dword columns per lane
    const size_t mat = blockIdx.x;
    const float* __restrict__ xm = x + mat * (size_t)(N * N);
    float* __restrict__ om = out + mat * (size_t)(N * N);

#pragma unroll
    for (int t = 0; t < 8; ++t) {
        const int r2 = wid * 8 + t;
        As_[r2 * NP + lane] = xm[r2 * N + lane];
        Vt_[r2 * NP + lane] = (r2 == lane) ? 1.0f : 0.0f;
    }
    __syncthreads();

    for (int sweep = 0; sweep < SWEEPS; ++sweep) {
        for (int r = 0; r < N - 1; ++r) {
            // ---- coefficients for this wave's 4 pairs (lanes 0..3);
            //      reads only rows/cols this wave owns -> no barrier ----
            float cv = 1.0f, sv = 0.0f;
            if (lane < 4) {
                const int i = wid * 4 + lane;
                int a = i - 1 + r; if (a >= 63) a -= 63;
                const int p = (i == 0) ? 0 : 1 + a;
                int b = 62 - i + r; if (b >= 63) b -= 63;
                const int q = 1 + b;
                const float app = As_[p * NP + p];
                const float aqq = As_[q * NP + q];
                const float apq = As_[p * NP + q];
                // branchless fast-math rotation coefficients
                const float tau = (aqq - app) * (0.5f * __builtin_amdgcn_rcpf(apq));
                const float at  = fabsf(tau);
                float t2 = __builtin_amdgcn_rcpf(at + __builtin_amdgcn_sqrtf(fmaf(at, at, 1.0f)));
                t2 = copysignf(t2, tau);
                const float cc = __builtin_amdgcn_rsqf(fmaf(t2, t2, 1.0f));
                const bool tiny = !(fabsf(apq) > 1e-30f);
                cv = tiny ? 1.0f : cc;
                sv = tiny ? 0.0f : t2 * cc;
            }
            // (c,s) -> SGPR broadcasts; col-phase pair indices -> SALU
            float ca[4], sa[4];
#pragma unroll
            for (int ii = 0; ii < 4; ++ii) {
                ca[ii] = __uint_as_float(__builtin_amdgcn_readlane(__float_as_uint(cv), ii));
                sa[ii] = __uint_as_float(__builtin_amdgcn_readlane(__float_as_uint(sv), ii));
            }
            int pa[4], qa[4];
#pragma unroll
            for (int ii = 0; ii < 4; ++ii) {
                const int i = wid * 4 + ii;
                int a = i - 1 + r; if (a >= 63) a -= 63;
                pa[ii] = (i == 0) ? 0 : 1 + a;
                int b = 62 - i + r; if (b >= 63) b -= 63;
                qa[ii] = 1 + b;
            }
            // per-lane pair indices/coeffs for the two half-wave groups:
            // group g handles pair i = wid*4 + 2g + half on this lane
            int pg[2], qg[2];
            float cg[2], sg[2];
#pragma unroll
            for (int g = 0; g < 2; ++g) {
                const int i = wid * 4 + 2 * g + half;
                int a = i - 1 + r; if (a >= 63) a -= 63;
                pg[g] = (i == 0) ? 0 : 1 + a;
                int b = 62 - i + r; if (b >= 63) b -= 63;
                qg[g] = 1 + b;
                cg[g] = half ? ca[2 * g + 1] : ca[2 * g];
                sg[g] = half ? sa[2 * g + 1] : sa[2 * g];
            }

            // ---- PHASE 1: A row rotation (both groups) + Vt group 0.
            //      Two adjacent dwords per lane (-> ds_read2/ds_write2).
            //      Gather all 12 dword-pairs first, then write all 12. ----
            {
                const float rp0x = As_[pg[0] * NP + c2], rp0y = As_[pg[0] * NP + c2 + 1];
                const float rq0x = As_[qg[0] * NP + c2], rq0y = As_[qg[0] * NP + c2 + 1];
                const float rp1x = As_[pg[1] * NP + c2], rp1y = As_[pg[1] * NP + c2 + 1];
                const float rq1x = As_[qg[1] * NP + c2], rq1y = As_[qg[1] * NP + c2 + 1];
                const float vp0x = Vt_[pg[0] * NP + c2], vp0y = Vt_[pg[0] * NP + c2 + 1];
                const float vq0x = Vt_[qg[0] * NP + c2], vq0y = Vt_[qg[0] * NP + c2 + 1];
                As_[pg[0] * NP + c2]     = cg[0] * rp0x - sg[0] * rq0x;
                As_[pg[0] * NP + c2 + 1] = cg[0] * rp0y - sg[0] * rq0y;
                As_[qg[0] * NP + c2]     = sg[0] * rp0x + cg[0] * rq0x;
                As_[qg[0] * NP + c2 + 1] = sg[0] * rp0y + cg[0] * rq0y;
                As_[pg[1] * NP + c2]     = cg[1] * rp1x - sg[1] * rq1x;
                As_[pg[1] * NP + c2 + 1] = cg[1] * rp1y - sg[1] * rq1y;
                As_[qg[1] * NP + c2]     = sg[1] * rp1x + cg[1] * rq1x;
                As_[qg[1] * NP + c2 + 1] = sg[1] * rp1y + cg[1] * rq1y;
                Vt_[pg[0] * NP + c2]     = cg[0] * vp0x - sg[0] * vq0x;
                Vt_[pg[0] * NP + c2 + 1] = cg[0] * vp0y - sg[0] * vq0y;
                Vt_[qg[0] * NP + c2]     = sg[0] * vp0x + cg[0] * vq0x;
                Vt_[qg[0] * NP + c2 + 1] = sg[0] * vp0y + cg[0] * vq0y;
            }
            __syncthreads();

            // ---- PHASE 2: A col rotation (4 pairs, b32, banks (lane+p)%32
            //      conflict-free at odd pitch) + Vt group 1 ----
            {
                float cp[4], cq[4];
#pragma unroll
                for (int ii = 0; ii < 4; ++ii) {
                    cp[ii] = As_[lane * NP + pa[ii]];
                    cq[ii] = As_[lane * NP + qa[ii]];
                }
                const float vp1x = Vt_[pg[1] * NP + c2], vp1y = Vt_[pg[1] * NP + c2 + 1];
                const float vq1x = Vt_[qg[1] * NP + c2], vq1y = Vt_[qg[1] * NP + c2 + 1];
#pragma unroll
                for (int ii = 0; ii < 4; ++ii) {
                    As_[lane * NP + pa[ii]] = ca[ii] * cp[ii] - sa[ii] * cq[ii];
                    As_[lane * NP + qa[ii]] = sa[ii] * cp[ii] + ca[ii] * cq[ii];
                }
                Vt_[pg[1] * NP + c2]     = cg[1] * vp1x - sg[1] * vq1x;
                Vt_[pg[1] * NP + c2 + 1] = cg[1] * vp1y - sg[1] * vq1y;
                Vt_[qg[1] * NP + c2]     = sg[1] * vp1x + cg[1] * vq1x;
                Vt_[qg[1] * NP + c2 + 1] = sg[1] * vp1y + cg[1] * vq1y;
            }
            __syncthreads();
        }
    }

    // A is dead from here -> overlay Rayleigh partials on its storage.
    double2* part = reinterpret_cast<double2*>(As_);  // 7*64*16 B < 16.6 KB

    // ---- fp64 Rayleigh vs ORIGINAL input; eigvec `lane` = Vt row `lane`;
    //      each wave covers 8 rows of the quadratic form ----
    const int r0 = wid * 8;
    {
        float vr[8];
#pragma unroll
        for (int t = 0; t < 8; ++t) vr[t] = Vt_[lane * NP + r0 + t];
        double nrm = 0.0, acc = 0.0;
#pragma unroll
        for (int t = 0; t < 8; ++t) nrm += (double)vr[t] * (double)vr[t];
        for (int c = 0; c < N; ++c) {
            const double vc = (double)Vt_[lane * NP + c];
            double inner = 0.0;
#pragma unroll
            for (int t = 0; t < 8; ++t)
                inner += (double)xm[(r0 + t) * N + c] * (double)vr[t];
            acc += vc * inner;
        }
        if (wid > 0) part[(wid - 1) * N + lane] = make_double2(acc, nrm);
        __syncthreads();
        if (wid == 0) {
#pragma unroll
            for (int k = 0; k < 7; ++k) {
                acc += part[k * N + lane].x;
                nrm += part[k * N + lane].y;
            }
            double wv = acc / nrm;
            wv = fmin(fmax(wv, (double)EPSV), (double)MAXEIG);
            farr[lane] = (float)log(wv);
        }
    }
    __syncthreads();

    // ---- reconstruct Out[r][lane] = sum_j Vt[j][r] * f_j * Vt[j][lane];
    //      8 rows per wave; Vt[j][r0+t] is a uniform broadcast read ----
    {
        float acc8[8];
#pragma unroll
        for (int t = 0; t < 8; ++t) acc8[t] = 0.0f;
        for (int j = 0; j < N; ++j) {
            const float gj = Vt_[j * NP + lane] * farr[j];
#pragma unroll
            for (int t = 0; t < 8; ++t)
                acc8[t] += Vt_[j * NP + r0 + t] * gj;
        }
#pragma unroll
        for (int t = 0; t < 8; ++t)
            om[(r0 + t) * N + lane] = acc8[t];
    }
}

extern "C" void kernel_launch(void* const* d_in, const int* in_sizes, int n_in,
                              void* d_out, int out_size, void* d_ws, size_t ws_size,
                              hipStream_t stream) {
    const float* x = (const float*)d_in[0];
    float* out = (float*)d_out;
    const int nmat = in_sizes[0] / (N * N);
    spd_log_kernel<<<dim3(nmat), dim3(512), 0, stream>>>(x, out);
}

// Round 14
// 1702.009 us; speedup vs baseline: 2.4075x; 2.3627x over previous
//
#include <hip/hip_runtime.h>
#include <math.h>

#define MIN_SWEEPS 6
#define MAX_SWEEPS 9
#define EPSV 1e-3
#define MAXEIG 1000.0

// ONE 64-lane wave per 64x64 symmetric matrix. ONE-SIDED Jacobi, all in
// registers, ZERO barriers in the main loop.
//   B = A + gamma*I (gamma = 0.5*||A||_F makes B PSD for this data class:
//   semicircle ||A||_2 ~ 0.25*||A||_F). Lane j owns column w_j of W (init B)
//   as 64 NAMED float registers (X-macro: no arrays -> no scratch demotion,
//   the round-1/2 spill trap). Round m (m=1..63): partner = lane^m via
//   ds_bpermute; Gram cross-dot computed identically on both partners
//   (products commute -> bitwise-equal (c,s) both sides); rotate own column.
//   All pairs covered once per 63-round sweep (XOR tournament).
//   At convergence w_j = (lambda_j + gamma) v_j -> v_j = w_j/||w_j||.
//   Eigenvalues from fp64 Rayleigh v^T A v on the ORIGINAL input (anchors
//   log near the clamp; norm-based sigma would carry fp32 drift ~1e-4).
// Rationale vs rounds 9-13: the LDS-resident two-sided structure floors at
// ~3400us (both pipes ~60%, 756 barriers); this cuts LDS ops 6x, VALU 3x,
// barriers to zero. LDS is used only by the tiny epilogue.
// Adaptive sweeps: 6 always, up to 9, per-WAVE exit (no cross-wave coupling)
// gated on off-diag Gram Frobenius^2 measured during the sweep.

#define REP64(X) \
  X(0) X(1) X(2) X(3) X(4) X(5) X(6) X(7) \
  X(8) X(9) X(10) X(11) X(12) X(13) X(14) X(15) \
  X(16) X(17) X(18) X(19) X(20) X(21) X(22) X(23) \
  X(24) X(25) X(26) X(27) X(28) X(29) X(30) X(31) \
  X(32) X(33) X(34) X(35) X(36) X(37) X(38) X(39) \
  X(40) X(41) X(42) X(43) X(44) X(45) X(46) X(47) \
  X(48) X(49) X(50) X(51) X(52) X(53) X(54) X(55) \
  X(56) X(57) X(58) X(59) X(60) X(61) X(62) X(63)

__global__ __launch_bounds__(64, 2)   // VGPR cap 256; we need ~155
void spd_log_kernel(const float* __restrict__ x, float* __restrict__ out) {
    __shared__ float vlds[64 * 65];   // epilogue only: V rows, pitch 65

    const int lane = (int)threadIdx.x;
    const size_t mat = blockIdx.x;
    const float* __restrict__ xm = x + mat * (size_t)4096;
    float* __restrict__ om = out + mat * (size_t)4096;

#define DECLW(i) float w##i;
    REP64(DECLW)
#define DECLQ(i) float q##i;
    REP64(DECLQ)

    // load my column of A (coalesced per element index)
#define LOADW(i) w##i = xm[(i) * 64 + lane];
    REP64(LOADW)

    // gamma = 0.5 * ||A||_F  (wave-reduced sum of squares)
    float ff = 0.0f;
#define ACCF(i) ff = fmaf(w##i, w##i, ff);
    REP64(ACCF)
#pragma unroll
    for (int o = 32; o > 0; o >>= 1) ff += __shfl_xor(ff, o);
    const float gamma = 0.5f * sqrtf(ff);

    // B = A + gamma*I : element [lane] of my column
#define SHIFTW(i) w##i += ((i) == lane) ? gamma : 0.0f;
    REP64(SHIFTW)

    float n = 0.0f;
#define ACCN(i) n = fmaf(w##i, w##i, n);
    REP64(ACCN)

    // ---------------- one-sided Jacobi sweeps (no barriers) ----------------
    for (int sweep = 0; sweep < MAX_SWEEPS; ++sweep) {
        // fresh norm (kills recurrence drift) + problem scale S
        n = 0.0f;
        REP64(ACCN)
        float S = n;
#pragma unroll
        for (int o = 32; o > 0; o >>= 1) S += __shfl_xor(S, o);
        float off2 = 0.0f;

        for (int m = 1; m < 64; ++m) {
            const int pidx = ((lane ^ m) << 2);
            // fetch partner column (64 bpermute, shared index reg)
#define FETCH(i) q##i = __int_as_float(__builtin_amdgcn_ds_bpermute(pidx, __float_as_int(w##i)));
            REP64(FETCH)
            // Gram cross-dot: identical value on both partners (a*b==b*a)
            float g = 0.0f;
#define ACCG(i) g = fmaf(w##i, q##i, g);
            REP64(ACCG)
            off2 = fmaf(g, g, off2);
            const float nq = __int_as_float(__builtin_amdgcn_ds_bpermute(pidx, __float_as_int(n)));
            const bool isp = lane < (lane ^ m);   // consistent p/q roles
            const float na = isp ? n : nq;
            const float nb = isp ? nq : n;
            // fast-math rotation zeroing the 2x2 Gram off-diagonal
            const float tau = (nb - na) * (0.5f * __builtin_amdgcn_rcpf(g));
            const float at  = fabsf(tau);
            float t = __builtin_amdgcn_rcpf(at + __builtin_amdgcn_sqrtf(fmaf(at, at, 1.0f)));
            t = copysignf(t, tau);
            float c = __builtin_amdgcn_rsqf(fmaf(t, t, 1.0f));
            float s = t * c;
            const bool tiny = !(fabsf(g) > 1e-28f);  // exact-0 / NaN guard
            c = tiny ? 1.0f : c;
            s = tiny ? 0.0f : s;
            const float tg = tiny ? 0.0f : t * g;
            const float se = isp ? -s : s;
            // rotate own column: p: c*w - s*q ; q: c*w + s*q
#define ROT(i) w##i = fmaf(se, q##i, c * w##i);
            REP64(ROT)
            // norm recurrence: n_p -= t*g ; n_q += t*g
            n += isp ? -tg : tg;
        }
        // wave-local convergence: exit earliest after MIN_SWEEPS
#pragma unroll
        for (int o = 32; o > 0; o >>= 1) off2 += __shfl_xor(off2, o);
        if (sweep >= MIN_SWEEPS - 1 && off2 < 1e-13f * S * S) break;
    }

    // ---------------- epilogue ----------------
    // v = w / ||w||
    n = 0.0f;
    REP64(ACCN)
    const float rn = __builtin_amdgcn_rsqf(n);
#define NRM(i) w##i *= rn;
    REP64(NRM)

    // dump v to LDS row `lane` (banks (lane+k)%32: 2-way, free)
#define DUMP(i) vlds[lane * 65 + (i)] = w##i;
    REP64(DUMP)
    __syncthreads();

    // fp64 Rayleigh vs ORIGINAL A: lambda = v^T A v  (||v|| = 1)
    double acc = 0.0;
    for (int r = 0; r < 64; ++r) {
        double inner = 0.0;
#define RAY(i) inner = fma((double)xm[r * 64 + (i)], (double)w##i, inner);
        REP64(RAY)
        const float vr = vlds[lane * 65 + r];
        acc = fma((double)vr, inner, acc);
    }
    double lam = fmin(fmax(acc, (double)EPSV), (double)MAXEIG);
    const float f = (float)log(lam);

    // q_j <- f_j * v_j[lane]  (transpose read, 2-way free; f_j via readlane)
#define G2(i) q##i = __uint_as_float(__builtin_amdgcn_readlane(__float_as_uint(f), (i))) * vlds[(i) * 65 + lane];
    REP64(G2)

    // Out[r][lane] = sum_j v_j[r] * q_j ; v_j[r] is a broadcast LDS read
    for (int r = 0; r < 64; ++r) {
        float a = 0.0f;
#define REC(i) a = fmaf(vlds[(i) * 65 + r], q##i, a);
        REP64(REC)
        om[r * 64 + lane] = a;
    }
}

extern "C" void kernel_launch(void* const* d_in, const int* in_sizes, int n_in,
                              void* d_out, int out_size, void* d_ws, size_t ws_size,
                              hipStream_t stream) {
    const float* x = (const float*)d_in[0];
    float* out = (float*)d_out;
    const int nmat = in_sizes[0] / 4096;
    spd_log_kernel<<<dim3(nmat), dim3(64), 0, stream>>>(x, out);
}